// Round 1
// baseline (1999.162 us; speedup 1.0000x reference)
//
#include <hip/hip_runtime.h>
#include <hip/hip_bf16.h>
#include <cmath>

#define DEV __device__ __forceinline__

typedef short s16x8 __attribute__((ext_vector_type(8)));
typedef float f32x4 __attribute__((ext_vector_type(4)));

DEV unsigned short f2bu(float x){
  __hip_bfloat16 h = __float2bfloat16(x);
  return *reinterpret_cast<unsigned short*>(&h);
}
DEV float bs2f(unsigned short v){ return __uint_as_float(((unsigned)v)<<16); }
DEV float bs2f(short v){ return bs2f((unsigned short)v); }

// ---------------------------------------------------------------------------
// K1: positional encoding pe[b,t,64], te-derived gate vectors U[b,t,6,64], decay
// ---------------------------------------------------------------------------
__global__ void k1_pe_u(const float* __restrict__ x, const float* __restrict__ delta_t,
                        const float* __restrict__ Wz, const float* __restrict__ bz,
                        const float* __restrict__ Wr, const float* __restrict__ br,
                        const float* __restrict__ Wc, const float* __restrict__ bc,
                        float* __restrict__ pe, float* __restrict__ U, float* __restrict__ decay)
{
  const int bt = blockIdx.x;           // b*256 + t
  const int d  = threadIdx.x;          // 0..63
  __shared__ float pes[64];
  float tmv = x[(size_t)bt*129 + 128]; // times
  int j = d & 31;
  float ts = (float)pow(256.0, (double)j * (1.0/31.0));
  float st = tmv / ts;
  float v = (d < 32) ? sinf(st) : cosf(st);
  pes[d] = v;
  pe[(size_t)bt*64 + d] = v;
  __syncthreads();
  float a0=bz[d], a1=0.f, a2=br[d], a3=0.f, a4=bc[d], a5=0.f;
  for (int k=0;k<64;k++){
    float p = pes[k];
    a0 = fmaf(p, Wz[(128+k)*64+d], a0);
    a1 = fmaf(p, Wz[(320+k)*64+d], a1);
    a2 = fmaf(p, Wr[(128+k)*64+d], a2);
    a3 = fmaf(p, Wr[(320+k)*64+d], a3);
    a4 = fmaf(p, Wc[(128+k)*64+d], a4);
    a5 = fmaf(p, Wc[(320+k)*64+d], a5);
  }
  float* u = U + (size_t)bt*384;
  u[d]=a0; u[64+d]=a1; u[128+d]=a2; u[192+d]=a3; u[256+d]=a4; u[320+d]=a5;
  if (d==0) decay[bt] = expf(-fmaxf(delta_t[bt], 0.f));
}

// ---------------------------------------------------------------------------
// K2a: qf = xf@WQ_f, kf = xf@WK_f   (xf[b,n,t] = nufft[b,1,t,n])
// ---------------------------------------------------------------------------
__global__ void k2a_qfkf(const float* __restrict__ nufft, const float* __restrict__ WQf,
                         const float* __restrict__ WKf, float* __restrict__ qf, float* __restrict__ kf)
{
  const int bn = blockIdx.x, b = bn>>6, n = bn&63;
  const int u = threadIdx.x;  // 0..255
  __shared__ float xs[256];
  xs[u] = nufft[ ((((size_t)b*2)+1)*256 + u)*64 + n ];
  __syncthreads();
  float aq=0.f, ak=0.f;
  for (int t=0;t<256;t++){
    float xv = xs[t];
    aq = fmaf(xv, WQf[t*256+u], aq);
    ak = fmaf(xv, WKf[t*256+u], ak);
  }
  qf[(size_t)bn*256+u]=aq;
  kf[(size_t)bn*256+u]=ak;
}

// ---------------------------------------------------------------------------
// K2b: per-batch S=relu(qf·kf)/16, row-softmax -> soft[b,64,64]
// ---------------------------------------------------------------------------
__launch_bounds__(256, 1)
__global__ void k2b_soft(const float* __restrict__ qf, const float* __restrict__ kf,
                         float* __restrict__ soft)
{
  const int b = blockIdx.x, tid = threadIdx.x;
  __shared__ float qs[64*257];
  __shared__ float ksh[64*257];
  __shared__ float Ss[64*65];
  const float* qb = qf + ((size_t)b<<14);
  const float* kb = kf + ((size_t)b<<14);
  for (int e=tid; e<16384; e+=256){
    int r=e>>8, c=e&255;
    qs[r*257+c]=qb[e];
    ksh[r*257+c]=kb[e];
  }
  __syncthreads();
  const int n = tid>>2, m0 = (tid&3)<<4;
  float acc[16];
  #pragma unroll
  for (int i=0;i<16;i++) acc[i]=0.f;
  for (int t=0;t<256;t++){
    float qv = qs[n*257+t];
    #pragma unroll
    for (int i=0;i<16;i++) acc[i] = fmaf(qv, ksh[(m0+i)*257+t], acc[i]);
  }
  #pragma unroll
  for (int i=0;i<16;i++) Ss[n*65+m0+i] = fmaxf(acc[i],0.f)*(1.f/16.f);
  __syncthreads();
  if (tid < 64){
    float mx=-1e30f;
    for (int m=0;m<64;m++) mx=fmaxf(mx, Ss[tid*65+m]);
    float s=0.f;
    for (int m=0;m<64;m++) s += expf(Ss[tid*65+m]-mx);
    float inv=1.f/s;
    for (int m=0;m<64;m++) soft[((size_t)b<<12)+(tid<<6)+m] = expf(Ss[tid*65+m]-mx)*inv;
  }
}

// ---------------------------------------------------------------------------
// K2c: A = 0.5(sm+sm^T) with sm = softmax(0.5(A0+A0^T)); A0 = mean_b soft.
//      Writes A (bf16) and row-sums rs (f32).
// ---------------------------------------------------------------------------
__global__ void k2c_A(const float* __restrict__ soft, short* __restrict__ Abf,
                      float* __restrict__ rs_out)
{
  const int tid = threadIdx.x; // 256
  __shared__ float A0[64*65];
  __shared__ float A1[64*65];
  for (int e=tid; e<4096; e+=256){
    int nn=e>>6, mm=e&63;
    float s=0.f;
    #pragma unroll
    for (int b=0;b<16;b++) s += soft[((size_t)b<<12)+e];
    A0[nn*65+mm] = s*(1.f/16.f);
  }
  __syncthreads();
  for (int e=tid; e<4096; e+=256){
    int nn=e>>6, mm=e&63;
    A1[nn*65+mm] = 0.5f*(A0[nn*65+mm]+A0[mm*65+nn]);
  }
  __syncthreads();
  if (tid < 64){
    float mx=-1e30f;
    for (int m=0;m<64;m++) mx=fmaxf(mx, A1[tid*65+m]);
    float s=0.f;
    for (int m=0;m<64;m++) s += expf(A1[tid*65+m]-mx);
    float inv=1.f/s;
    for (int m=0;m<64;m++) A0[tid*65+m] = expf(A1[tid*65+m]-mx)*inv;
  }
  __syncthreads();
  for (int e=tid; e<4096; e+=256){
    int nn=e>>6, mm=e&63;
    float a = 0.5f*(A0[nn*65+mm]+A0[mm*65+nn]);
    A1[nn*65+mm] = a;
    Abf[e] = (short)f2bu(a);
  }
  __syncthreads();
  if (tid < 64){
    float s=0.f;
    for (int m=0;m<64;m++) s += A1[tid*65+m];
    rs_out[tid]=s;
  }
}

// ---------------------------------------------------------------------------
// K3: per-(b,n) transformer head -> x_tat (bf16). fp32 vector, thread = q-row.
// ---------------------------------------------------------------------------
DEV void ln_row(float* h, const float* g, const float* bb){
  float mu=0.f;
  #pragma unroll
  for (int d=0;d<64;d++) mu += h[d];
  mu *= 0.015625f;
  float var=0.f;
  #pragma unroll
  for (int d=0;d<64;d++){ float c=h[d]-mu; var = fmaf(c,c,var); }
  var *= 0.015625f;
  float r = 1.f/sqrtf(var+1e-5f);
  #pragma unroll
  for (int d=0;d<64;d++) h[d] = (h[d]-mu)*r*g[d] + bb[d];
}

__launch_bounds__(256, 1)
__global__ void k3_former(const float* __restrict__ x, const float* __restrict__ pe,
    const float* __restrict__ proj_w, const float* __restrict__ proj_b,
    const float* __restrict__ Wqkv, const float* __restrict__ bqkv,
    const float* __restrict__ Wo, const float* __restrict__ bo,
    const float* __restrict__ ln1g, const float* __restrict__ ln1b,
    const float* __restrict__ W1, const float* __restrict__ b1,
    const float* __restrict__ W2, const float* __restrict__ b2,
    const float* __restrict__ ln2g, const float* __restrict__ ln2b,
    const int* __restrict__ lengths, unsigned short* __restrict__ xtat)
{
  const int bn = blockIdx.x, b = bn>>6, n = bn&63;
  const int tid = threadIdx.x;
  __shared__ unsigned short tins[256][72];   // row stride 144B: 16B-aligned rows
  __shared__ unsigned short ksh[256][72];
  __shared__ unsigned short vsh[256][72];
  __shared__ float valr[256], obsr[256];
  int len = lengths[b]; if (len < 1) len = 1;
  {
    const float* xr = x + ((size_t)b*256+tid)*129;
    valr[tid] = xr[n];
    obsr[tid] = xr[64+n];
  }
  __syncthreads();
  for (int e=tid; e<16384; e+=256){
    int t=e>>6, d=e&63;
    float ti = valr[t]*proj_w[d] + obsr[t]*proj_w[64+d] + proj_b[d]
             + pe[((size_t)b*256+t)*64+d];
    tins[t][d] = f2bu(ti);
  }
  __syncthreads();
  if (tid < len){
    float ak[64], av[64];
    #pragma unroll
    for (int d=0;d<64;d++){ ak[d]=bqkv[64+d]; av[d]=bqkv[128+d]; }
    for (int kk=0;kk<64;kk++){
      float tv = bs2f(tins[tid][kk]);
      const float* wr = Wqkv + kk*192;
      #pragma unroll
      for (int d=0;d<64;d++){
        ak[d] = fmaf(tv, wr[64+d], ak[d]);
        av[d] = fmaf(tv, wr[128+d], av[d]);
      }
    }
    #pragma unroll
    for (int d=0;d<64;d++){ ksh[tid][d]=f2bu(ak[d]); vsh[tid][d]=f2bu(av[d]); }
  }
  __syncthreads();
  if (tid < len){
    // q row (scale 1/8 folded in)
    float q[64];
    #pragma unroll
    for (int d=0;d<64;d++) q[d]=bqkv[d];
    for (int kk=0;kk<64;kk++){
      float tv = bs2f(tins[tid][kk]);
      const float* wr = Wqkv + kk*192;
      #pragma unroll
      for (int d=0;d<64;d++) q[d] = fmaf(tv, wr[d], q[d]);
    }
    #pragma unroll
    for (int d=0;d<64;d++) q[d] *= 0.125f;
    // online-softmax attention over keys j<len (scores are O(0.1): no max needed)
    float xo[64];
    #pragma unroll
    for (int d=0;d<64;d++) xo[d]=0.f;
    float l=0.f;
    for (int j=0;j<len;j++){
      const unsigned short* kr = &ksh[j][0];
      float sp[8]={0,0,0,0,0,0,0,0};
      #pragma unroll
      for (int c=0;c<8;c++){
        s16x8 kv = *(const s16x8*)(kr + c*8);
        #pragma unroll
        for (int e=0;e<8;e++) sp[e] = fmaf(q[c*8+e], bs2f(kv[e]), sp[e]);
      }
      float s = ((sp[0]+sp[1])+(sp[2]+sp[3]))+((sp[4]+sp[5])+(sp[6]+sp[7]));
      float p = __expf(s);
      l += p;
      const unsigned short* vr = &vsh[j][0];
      #pragma unroll
      for (int c=0;c<8;c++){
        s16x8 vv = *(const s16x8*)(vr + c*8);
        #pragma unroll
        for (int e=0;e<8;e++) xo[c*8+e] = fmaf(p, bs2f(vv[e]), xo[c*8+e]);
      }
    }
    float inv = 1.f/l;
    // h1 = LN(tin + ao@Wo + bo)
    float h1r[64];
    #pragma unroll
    for (int d=0;d<64;d++) h1r[d] = bo[d] + bs2f(tins[tid][d]);
    for (int kk=0;kk<64;kk++){
      float xv = xo[kk]*inv;
      const float* wr = Wo + kk*64;
      #pragma unroll
      for (int d=0;d<64;d++) h1r[d] = fmaf(xv, wr[d], h1r[d]);
    }
    ln_row(h1r, ln1g, ln1b);
    // ff
    float f1[64];
    #pragma unroll
    for (int d=0;d<64;d++) f1[d]=b1[d];
    for (int kk=0;kk<64;kk++){
      float hv = h1r[kk];
      const float* wr = W1 + kk*64;
      #pragma unroll
      for (int d=0;d<64;d++) f1[d] = fmaf(hv, wr[d], f1[d]);
    }
    #pragma unroll
    for (int d=0;d<64;d++) f1[d]=fmaxf(f1[d],0.f);
    float to[64];
    #pragma unroll
    for (int d=0;d<64;d++) to[d]=h1r[d]+b2[d];
    for (int kk=0;kk<64;kk++){
      float fv = f1[kk];
      const float* wr = W2 + kk*64;
      #pragma unroll
      for (int d=0;d<64;d++) to[d] = fmaf(fv, wr[d], to[d]);
    }
    ln_row(to, ln2g, ln2b);
    float ob = obsr[tid];
    unsigned short* xw = xtat + (((size_t)bn)*256+tid)*64;
    #pragma unroll
    for (int d=0;d<64;d++)
      xw[d] = f2bu(ob*bs2f(tins[tid][d]) + (1.f-ob)*to[d]);
  }
}

// ---------------------------------------------------------------------------
// K4: graph-GRU scan, one block per batch, 8 waves, bf16 MFMA 16x16x32.
//     LDS 64x64 bf16 tiles, XOR-swizzled (byte ^= (row&7)<<4 within 128B row).
// ---------------------------------------------------------------------------
DEV int swzo(int row, int col){   // short-index into swizzled [64][64] bf16 tile
  return (row*128 + ((col*2) ^ ((row&7)<<4))) >> 1;
}
DEV s16x8 ldfrag(const short* tile, int t16, int lane, int kk){
  int row = t16 + (lane & 15);
  int c0  = (kk<<5) + ((lane>>4)<<3);
  int off = (row*128 + ((c0<<1) ^ ((row&7)<<4))) >> 1;
  return *(const s16x8*)(tile + off);
}

__launch_bounds__(512, 1)
__global__ void k4_scan(const unsigned short* __restrict__ xtat, const float* __restrict__ U,
                        const float* __restrict__ decay, const short* __restrict__ Abf,
                        const float* __restrict__ rs_g,
                        const float* __restrict__ Wz, const float* __restrict__ Wr,
                        const float* __restrict__ Wc,
                        const int* __restrict__ lengths, float* __restrict__ hT)
{
  const int b = blockIdx.x;
  const int tid = threadIdx.x;
  const int w = tid >> 6, lane = tid & 63;
  const int tn = w & 3, tm0 = (w >> 2) << 1;       // wave -> col-tile tn, row-tiles tm0,tm0+1
  const int colg = (tn<<4) + (lane & 15);
  const int rsub = (lane >> 4) << 2;

  __shared__ short h_rm[4096], h_tp[4096], xt_rm[4096], xt_tp[4096];
  __shared__ short rh_rm[4096], rh_tp[4096], axt_s[4096], ah_s[4096], arh_s[4096];
  __shared__ float dec_s[256];
  __shared__ float rs_s[64];

  int len = lengths[b]; if (len < 1) len = 1;
  for (int e=tid; e<256; e+=512) dec_s[e] = decay[b*256+e];
  if (tid < 64) rs_s[tid] = rs_g[tid];

  // static A-operand frags of the graph matrix A
  s16x8 aA[2][2];
  #pragma unroll
  for (int ti=0;ti<2;ti++)
    #pragma unroll
    for (int kk=0;kk<2;kk++)
      aA[ti][kk] = *(const s16x8*)(Abf + (((tm0+ti)<<4) + (lane&15))*64 + (kk<<5) + ((lane>>4)<<3));

  // static B-operand frags of the 12 weight slices (bf16-converted from f32)
  // order: zx1 zh1 zx2 zh2 | rx1 rh1 rx2 rh2 | cx1 ch1 cx2 ch2
  s16x8 wf[12][2];
  {
    const float* Wg[3] = {Wz, Wr, Wc};
    const int offs[4] = {0, 64, 192, 256};
    #pragma unroll
    for (int g3=0; g3<3; g3++)
      #pragma unroll
      for (int s4=0; s4<4; s4++)
        #pragma unroll
        for (int kk=0; kk<2; kk++){
          s16x8 tf;
          int kb = (kk<<5) + ((lane>>4)<<3);
          #pragma unroll
          for (int j=0;j<8;j++)
            tf[j] = (short)f2bu(Wg[g3][(offs[s4]+kb+j)*64 + colg]);
          wf[g3*4+s4][kk] = tf;
        }
  }

  f32x4 hreg[2] = {{0.f,0.f,0.f,0.f},{0.f,0.f,0.f,0.f}};
  const int xn  = tid >> 3;
  const int xd0 = (tid & 7) << 3;
  __syncthreads();

  for (int t=0; t<256; t++){
    float dc = dec_s[t];
    #pragma unroll
    for (int ti=0;ti<2;ti++)
      #pragma unroll
      for (int i=0;i<4;i++) hreg[ti][i] *= dc;

    if (t < len){
      // stage decayed h (row-major + transposed) and xt tile
      #pragma unroll
      for (int ti=0;ti<2;ti++){
        int rb = ((tm0+ti)<<4) + rsub;
        #pragma unroll
        for (int i=0;i<4;i++){
          short hv = (short)f2bu(hreg[ti][i]);
          h_rm[swzo(rb+i, colg)] = hv;
          h_tp[swzo(colg, rb+i)] = hv;
        }
      }
      {
        const s16x8 vv = *(const s16x8*)((const short*)xtat + (((size_t)(b*64+xn))*256 + t)*64 + xd0);
        *(s16x8*)(xt_rm + swzo(xn, xd0)) = vv;
        #pragma unroll
        for (int j=0;j<8;j++) xt_tp[swzo(xd0+j, xn)] = vv[j];
      }
      __syncthreads();

      // group A: Axt = A@xt, Ah = A@h
      {
        f32x4 ax[2] = {{0,0,0,0},{0,0,0,0}}, ahh[2] = {{0,0,0,0},{0,0,0,0}};
        #pragma unroll
        for (int kk=0;kk<2;kk++){
          s16x8 bx = ldfrag(xt_tp, tn<<4, lane, kk);
          s16x8 bh = ldfrag(h_tp,  tn<<4, lane, kk);
          #pragma unroll
          for (int ti=0;ti<2;ti++){
            ax[ti]  = __builtin_amdgcn_mfma_f32_16x16x32_bf16(aA[ti][kk], bx, ax[ti], 0,0,0);
            ahh[ti] = __builtin_amdgcn_mfma_f32_16x16x32_bf16(aA[ti][kk], bh, ahh[ti], 0,0,0);
          }
        }
        #pragma unroll
        for (int ti=0;ti<2;ti++){
          int rb = ((tm0+ti)<<4) + rsub;
          #pragma unroll
          for (int i=0;i<4;i++){
            axt_s[swzo(rb+i, colg)] = (short)f2bu(ax[ti][i]);
            ah_s [swzo(rb+i, colg)] = (short)f2bu(ahh[ti][i]);
          }
        }
      }
      __syncthreads();

      const float* ub = U + ((size_t)(b*256+t))*384;
      float u1z=ub[colg], u2z=ub[64+colg], u1r=ub[128+colg], u2r=ub[192+colg];
      float u1c=ub[256+colg], u2c=ub[320+colg];

      // gates z, r
      f32x4 gz[2] = {{0,0,0,0},{0,0,0,0}}, gr[2] = {{0,0,0,0},{0,0,0,0}};
      #pragma unroll
      for (int ti=0;ti<2;ti++){
        int rt = (tm0+ti)<<4;
        #pragma unroll
        for (int kk=0;kk<2;kk++){
          s16x8 fxt = ldfrag(xt_rm, rt, lane, kk);
          s16x8 fh  = ldfrag(h_rm,  rt, lane, kk);
          s16x8 fax = ldfrag(axt_s, rt, lane, kk);
          s16x8 fah = ldfrag(ah_s,  rt, lane, kk);
          gz[ti] = __builtin_amdgcn_mfma_f32_16x16x32_bf16(fxt, wf[0][kk], gz[ti], 0,0,0);
          gz[ti] = __builtin_amdgcn_mfma_f32_16x16x32_bf16(fh,  wf[1][kk], gz[ti], 0,0,0);
          gz[ti] = __builtin_amdgcn_mfma_f32_16x16x32_bf16(fax, wf[2][kk], gz[ti], 0,0,0);
          gz[ti] = __builtin_amdgcn_mfma_f32_16x16x32_bf16(fah, wf[3][kk], gz[ti], 0,0,0);
          gr[ti] = __builtin_amdgcn_mfma_f32_16x16x32_bf16(fxt, wf[4][kk], gr[ti], 0,0,0);
          gr[ti] = __builtin_amdgcn_mfma_f32_16x16x32_bf16(fh,  wf[5][kk], gr[ti], 0,0,0);
          gr[ti] = __builtin_amdgcn_mfma_f32_16x16x32_bf16(fax, wf[6][kk], gr[ti], 0,0,0);
          gr[ti] = __builtin_amdgcn_mfma_f32_16x16x32_bf16(fah, wf[7][kk], gr[ti], 0,0,0);
        }
      }
      f32x4 zz[2];
      #pragma unroll
      for (int ti=0;ti<2;ti++){
        int rb = ((tm0+ti)<<4) + rsub;
        #pragma unroll
        for (int i=0;i<4;i++){
          float rsv = rs_s[rb+i];
          float gzv = gz[ti][i] + u1z + rsv*u2z;
          float grv = gr[ti][i] + u1r + rsv*u2r;
          float zv = 1.f/(1.f+__expf(-gzv));
          float rv = 1.f/(1.f+__expf(-grv));
          zz[ti][i] = zv;
          short rhv = (short)f2bu(rv * hreg[ti][i]);
          rh_rm[swzo(rb+i, colg)] = rhv;
          rh_tp[swzo(colg, rb+i)] = rhv;
        }
      }
      __syncthreads();

      // Arh = A @ (r*h)
      {
        f32x4 ar[2] = {{0,0,0,0},{0,0,0,0}};
        #pragma unroll
        for (int kk=0;kk<2;kk++){
          s16x8 brh = ldfrag(rh_tp, tn<<4, lane, kk);
          #pragma unroll
          for (int ti=0;ti<2;ti++)
            ar[ti] = __builtin_amdgcn_mfma_f32_16x16x32_bf16(aA[ti][kk], brh, ar[ti], 0,0,0);
        }
        #pragma unroll
        for (int ti=0;ti<2;ti++){
          int rb = ((tm0+ti)<<4) + rsub;
          #pragma unroll
          for (int i=0;i<4;i++)
            arh_s[swzo(rb+i, colg)] = (short)f2bu(ar[ti][i]);
        }
      }
      __syncthreads();

      // gate c + h update
      {
        f32x4 gc[2] = {{0,0,0,0},{0,0,0,0}};
        #pragma unroll
        for (int ti=0;ti<2;ti++){
          int rt = (tm0+ti)<<4;
          #pragma unroll
          for (int kk=0;kk<2;kk++){
            s16x8 fxt = ldfrag(xt_rm, rt, lane, kk);
            s16x8 frh = ldfrag(rh_rm, rt, lane, kk);
            s16x8 fax = ldfrag(axt_s, rt, lane, kk);
            s16x8 far = ldfrag(arh_s, rt, lane, kk);
            gc[ti] = __builtin_amdgcn_mfma_f32_16x16x32_bf16(fxt, wf[8][kk],  gc[ti], 0,0,0);
            gc[ti] = __builtin_amdgcn_mfma_f32_16x16x32_bf16(frh, wf[9][kk],  gc[ti], 0,0,0);
            gc[ti] = __builtin_amdgcn_mfma_f32_16x16x32_bf16(fax, wf[10][kk], gc[ti], 0,0,0);
            gc[ti] = __builtin_amdgcn_mfma_f32_16x16x32_bf16(far, wf[11][kk], gc[ti], 0,0,0);
          }
        }
        #pragma unroll
        for (int ti=0;ti<2;ti++){
          int rb = ((tm0+ti)<<4) + rsub;
          #pragma unroll
          for (int i=0;i<4;i++){
            float rsv = rs_s[rb+i];
            float gcv = gc[ti][i] + u1c + rsv*u2c;
            float cv = 1.f - 2.f/(__expf(2.f*gcv)+1.f);   // tanh
            float zv = zz[ti][i];
            hreg[ti][i] = zv*hreg[ti][i] + (1.f-zv)*cv;
          }
        }
      }
      __syncthreads();   // protect xt/h/aux tiles before next step's writes
    }
  }

  #pragma unroll
  for (int ti=0;ti<2;ti++){
    int rb = ((tm0+ti)<<4) + rsub;
    #pragma unroll
    for (int i=0;i<4;i++)
      hT[(((size_t)b<<6) + rb + i)*64 + colg] = hreg[ti][i];
  }
}

// ---------------------------------------------------------------------------
// K5: classifier head
// ---------------------------------------------------------------------------
__global__ void k5_head(const float* __restrict__ hT, const float* __restrict__ Wfin,
                        const float* __restrict__ bfin,
                        const float* __restrict__ stat, const float* __restrict__ We,
                        const float* __restrict__ be,
                        const float* __restrict__ Wc1, const float* __restrict__ bc1,
                        const float* __restrict__ Wc2, const float* __restrict__ bc2,
                        float* __restrict__ out)
{
  const int b = blockIdx.x, tid = threadIdx.x;
  __shared__ float cat[128];
  __shared__ float hcl[200];
  if (tid < 64){
    const float* hr = hT + (((size_t)b<<6)+tid)*64;
    float a = bfin[0];
    #pragma unroll
    for (int d=0;d<64;d++) a = fmaf(hr[d], Wfin[d], a);
    cat[tid]=a;
  } else if (tid < 128){
    int nn = tid-64;
    float a = be[nn];
    #pragma unroll
    for (int k=0;k<9;k++) a = fmaf(stat[b*9+k], We[k*64+nn], a);
    cat[tid]=a;
  }
  __syncthreads();
  if (tid < 200){
    float a = bc1[tid];
    for (int k=0;k<128;k++) a = fmaf(cat[k], Wc1[k*200+tid], a);
    hcl[tid] = fmaxf(a, 0.f);
  }
  __syncthreads();
  if (tid < 2){
    float a = bc2[tid];
    for (int k=0;k<200;k++) a = fmaf(hcl[k], Wc2[k*2+tid], a);
    out[b*2+tid] = a;
  }
}

// ---------------------------------------------------------------------------
extern "C" void kernel_launch(void* const* d_in, const int* in_sizes, int n_in,
                              void* d_out, int out_size, void* d_ws, size_t ws_size,
                              hipStream_t stream)
{
  const float* x       = (const float*)d_in[0];
  const float* nufft   = (const float*)d_in[1];
  const float* delta_t = (const float*)d_in[2];
  const float* stat    = (const float*)d_in[3];
  const int*   lengths = (const int*)  d_in[4];
  const float* proj_w  = (const float*)d_in[5];
  const float* proj_b  = (const float*)d_in[6];
  const float* Wqkv    = (const float*)d_in[7];
  const float* bqkv    = (const float*)d_in[8];
  const float* Wo      = (const float*)d_in[9];
  const float* bo      = (const float*)d_in[10];
  const float* ln1g    = (const float*)d_in[11];
  const float* ln1b    = (const float*)d_in[12];
  const float* W1      = (const float*)d_in[13];
  const float* b1      = (const float*)d_in[14];
  const float* W2      = (const float*)d_in[15];
  const float* b2      = (const float*)d_in[16];
  const float* ln2g    = (const float*)d_in[17];
  const float* ln2b    = (const float*)d_in[18];
  const float* WQf     = (const float*)d_in[19];
  const float* WKf     = (const float*)d_in[20];
  const float* Wz      = (const float*)d_in[21];
  const float* bz      = (const float*)d_in[22];
  const float* Wr      = (const float*)d_in[23];
  const float* br      = (const float*)d_in[24];
  const float* Wc      = (const float*)d_in[25];
  const float* bc      = (const float*)d_in[26];
  const float* Wfin    = (const float*)d_in[27];
  const float* bfin    = (const float*)d_in[28];
  const float* We      = (const float*)d_in[29];
  const float* be      = (const float*)d_in[30];
  const float* Wc1     = (const float*)d_in[31];
  const float* bc1     = (const float*)d_in[32];
  const float* Wc2     = (const float*)d_in[33];
  const float* bc2     = (const float*)d_in[34];
  float* out = (float*)d_out;

  char* ws = (char*)d_ws;
  size_t o = 0;
  float* pe    = (float*)(ws+o); o += (size_t)4096*64*4;       // 1 MB
  float* U     = (float*)(ws+o); o += (size_t)4096*384*4;      // 6 MB
  float* decay = (float*)(ws+o); o += (size_t)4096*4;          // 16 KB
  unsigned short* xtat = (unsigned short*)(ws+o); o += (size_t)1024*256*64*2; // 32 MB
  float* qf    = (float*)(ws+o); o += (size_t)1024*256*4;      // 1 MB
  float* kf    = (float*)(ws+o); o += (size_t)1024*256*4;      // 1 MB
  float* soft  = (float*)(ws+o); o += (size_t)16*4096*4;       // 256 KB
  short* Abf   = (short*)(ws+o); o += (size_t)4096*2;          // 8 KB
  float* rs    = (float*)(ws+o); o += (size_t)64*4;            // 256 B
  float* hT    = (float*)(ws+o); o += (size_t)16*64*64*4;      // 256 KB
  (void)ws_size; (void)in_sizes; (void)n_in; (void)out_size;

  hipLaunchKernelGGL(k1_pe_u,   dim3(4096), dim3(64),  0, stream,
                     x, delta_t, Wz, bz, Wr, br, Wc, bc, pe, U, decay);
  hipLaunchKernelGGL(k2a_qfkf,  dim3(1024), dim3(256), 0, stream,
                     nufft, WQf, WKf, qf, kf);
  hipLaunchKernelGGL(k2b_soft,  dim3(16),   dim3(256), 0, stream, qf, kf, soft);
  hipLaunchKernelGGL(k2c_A,     dim3(1),    dim3(256), 0, stream, soft, Abf, rs);
  hipLaunchKernelGGL(k3_former, dim3(1024), dim3(256), 0, stream,
                     x, pe, proj_w, proj_b, Wqkv, bqkv, Wo, bo, ln1g, ln1b,
                     W1, b1, W2, b2, ln2g, ln2b, lengths, xtat);
  hipLaunchKernelGGL(k4_scan,   dim3(16),   dim3(512), 0, stream,
                     xtat, U, decay, Abf, rs, Wz, Wr, Wc, lengths, hT);
  hipLaunchKernelGGL(k5_head,   dim3(16),   dim3(256), 0, stream,
                     hT, Wfin, bfin, stat, We, be, Wc1, bc1, Wc2, bc2, out);
}

// Round 2
// 1068.556 us; speedup vs baseline: 1.8709x; 1.8709x over previous
//
#include <hip/hip_runtime.h>
#include <hip/hip_bf16.h>
#include <cmath>

#define DEV __device__ __forceinline__

typedef short s16x8 __attribute__((ext_vector_type(8)));
typedef float f32x4 __attribute__((ext_vector_type(4)));

DEV unsigned short f2bu(float x){
  __hip_bfloat16 h = __float2bfloat16(x);
  return *reinterpret_cast<unsigned short*>(&h);
}
DEV float bs2f(unsigned short v){ return __uint_as_float(((unsigned)v)<<16); }
DEV float bs2f(short v){ return bs2f((unsigned short)v); }

// swizzled [R][64] bf16 tile helpers (row stride 128B, byte ^= (row&7)<<4)
DEV int swzo(int row, int col){
  return (row*128 + ((col*2) ^ ((row&7)<<4))) >> 1;
}
DEV s16x8 ldfrag(const short* tile, int t16, int lane, int kk){
  int row = t16 + (lane & 15);
  int c0  = (kk<<5) + ((lane>>4)<<3);
  int off = (row*128 + ((c0<<1) ^ ((row&7)<<4))) >> 1;
  return *(const s16x8*)(tile + off);
}
// swizzled [64][256] bf16 (V^T) tile: row stride 512B
DEV int swzv(int d, int t){
  return (d*512 + ((t*2) ^ ((d&7)<<4))) >> 1;
}

// ---------------------------------------------------------------------------
// K0: weight prep — bf16 transposes Wqkv_t[192][64], Wo_t/W1_t/W2_t[64][64]
// ---------------------------------------------------------------------------
__global__ void k0_prep(const float* __restrict__ Wqkv, const float* __restrict__ Wo,
                        const float* __restrict__ W1, const float* __restrict__ W2,
                        short* __restrict__ Wqkv_t, short* __restrict__ Wo_t,
                        short* __restrict__ W1_t, short* __restrict__ W2_t)
{
  int t = blockIdx.x*256 + threadIdx.x;
  if (t < 12288){ int nn=t>>6, k=t&63; Wqkv_t[t]=(short)f2bu(Wqkv[k*192+nn]); }
  else if (t < 16384){ int e=t-12288; int nn=e>>6,k=e&63; Wo_t[e]=(short)f2bu(Wo[k*64+nn]); }
  else if (t < 20480){ int e=t-16384; int nn=e>>6,k=e&63; W1_t[e]=(short)f2bu(W1[k*64+nn]); }
  else if (t < 24576){ int e=t-20480; int nn=e>>6,k=e&63; W2_t[e]=(short)f2bu(W2[k*64+nn]); }
}

// ---------------------------------------------------------------------------
// K1: positional encoding pe[b,t,64], te-derived gate vectors U[b,t,6,64], decay
// ---------------------------------------------------------------------------
__global__ void k1_pe_u(const float* __restrict__ x, const float* __restrict__ delta_t,
                        const float* __restrict__ Wz, const float* __restrict__ bz,
                        const float* __restrict__ Wr, const float* __restrict__ br,
                        const float* __restrict__ Wc, const float* __restrict__ bc,
                        float* __restrict__ pe, float* __restrict__ U, float* __restrict__ decay)
{
  const int bt = blockIdx.x;           // b*256 + t
  const int d  = threadIdx.x;          // 0..63
  __shared__ float pes[64];
  float tmv = x[(size_t)bt*129 + 128]; // times
  int j = d & 31;
  float ts = (float)pow(256.0, (double)j * (1.0/31.0));
  float st = tmv / ts;
  float v = (d < 32) ? sinf(st) : cosf(st);
  pes[d] = v;
  pe[(size_t)bt*64 + d] = v;
  __syncthreads();
  float a0=bz[d], a1=0.f, a2=br[d], a3=0.f, a4=bc[d], a5=0.f;
  for (int k=0;k<64;k++){
    float p = pes[k];
    a0 = fmaf(p, Wz[(128+k)*64+d], a0);
    a1 = fmaf(p, Wz[(320+k)*64+d], a1);
    a2 = fmaf(p, Wr[(128+k)*64+d], a2);
    a3 = fmaf(p, Wr[(320+k)*64+d], a3);
    a4 = fmaf(p, Wc[(128+k)*64+d], a4);
    a5 = fmaf(p, Wc[(320+k)*64+d], a5);
  }
  float* u = U + (size_t)bt*384;
  u[d]=a0; u[64+d]=a1; u[128+d]=a2; u[192+d]=a3; u[256+d]=a4; u[320+d]=a5;
  if (d==0) decay[bt] = expf(-fmaxf(delta_t[bt], 0.f));
}

// ---------------------------------------------------------------------------
// K2a: qf = xf@WQ_f, kf = xf@WK_f   (xf[b,n,t] = nufft[b,1,t,n])
// ---------------------------------------------------------------------------
__global__ void k2a_qfkf(const float* __restrict__ nufft, const float* __restrict__ WQf,
                         const float* __restrict__ WKf, float* __restrict__ qf, float* __restrict__ kf)
{
  const int bn = blockIdx.x, b = bn>>6, n = bn&63;
  const int u = threadIdx.x;  // 0..255
  __shared__ float xs[256];
  xs[u] = nufft[ ((((size_t)b*2)+1)*256 + u)*64 + n ];
  __syncthreads();
  float aq=0.f, ak=0.f;
  for (int t=0;t<256;t++){
    float xv = xs[t];
    aq = fmaf(xv, WQf[t*256+u], aq);
    ak = fmaf(xv, WKf[t*256+u], ak);
  }
  qf[(size_t)bn*256+u]=aq;
  kf[(size_t)bn*256+u]=ak;
}

// ---------------------------------------------------------------------------
// K2b: per-batch S=relu(qf·kf)/16, row-softmax -> soft[b,64,64]
// ---------------------------------------------------------------------------
__launch_bounds__(256, 1)
__global__ void k2b_soft(const float* __restrict__ qf, const float* __restrict__ kf,
                         float* __restrict__ soft)
{
  const int b = blockIdx.x, tid = threadIdx.x;
  __shared__ float qs[64*257];
  __shared__ float ksh[64*257];
  __shared__ float Ss[64*65];
  const float* qb = qf + ((size_t)b<<14);
  const float* kb = kf + ((size_t)b<<14);
  for (int e=tid; e<16384; e+=256){
    int r=e>>8, c=e&255;
    qs[r*257+c]=qb[e];
    ksh[r*257+c]=kb[e];
  }
  __syncthreads();
  const int n = tid>>2, m0 = (tid&3)<<4;
  float acc[16];
  #pragma unroll
  for (int i=0;i<16;i++) acc[i]=0.f;
  for (int t=0;t<256;t++){
    float qv = qs[n*257+t];
    #pragma unroll
    for (int i=0;i<16;i++) acc[i] = fmaf(qv, ksh[(m0+i)*257+t], acc[i]);
  }
  #pragma unroll
  for (int i=0;i<16;i++) Ss[n*65+m0+i] = fmaxf(acc[i],0.f)*(1.f/16.f);
  __syncthreads();
  if (tid < 64){
    float mx=-1e30f;
    for (int m=0;m<64;m++) mx=fmaxf(mx, Ss[tid*65+m]);
    float s=0.f;
    for (int m=0;m<64;m++) s += expf(Ss[tid*65+m]-mx);
    float inv=1.f/s;
    for (int m=0;m<64;m++) soft[((size_t)b<<12)+(tid<<6)+m] = expf(Ss[tid*65+m]-mx)*inv;
  }
}

// ---------------------------------------------------------------------------
// K2c: A = 0.5(sm+sm^T) with sm = softmax(0.5(A0+A0^T)); A0 = mean_b soft.
// ---------------------------------------------------------------------------
__global__ void k2c_A(const float* __restrict__ soft, short* __restrict__ Abf,
                      float* __restrict__ rs_out)
{
  const int tid = threadIdx.x; // 256
  __shared__ float A0[64*65];
  __shared__ float A1[64*65];
  for (int e=tid; e<4096; e+=256){
    int nn=e>>6, mm=e&63;
    float s=0.f;
    #pragma unroll
    for (int b=0;b<16;b++) s += soft[((size_t)b<<12)+e];
    A0[nn*65+mm] = s*(1.f/16.f);
  }
  __syncthreads();
  for (int e=tid; e<4096; e+=256){
    int nn=e>>6, mm=e&63;
    A1[nn*65+mm] = 0.5f*(A0[nn*65+mm]+A0[mm*65+nn]);
  }
  __syncthreads();
  if (tid < 64){
    float mx=-1e30f;
    for (int m=0;m<64;m++) mx=fmaxf(mx, A1[tid*65+m]);
    float s=0.f;
    for (int m=0;m<64;m++) s += expf(A1[tid*65+m]-mx);
    float inv=1.f/s;
    for (int m=0;m<64;m++) A0[tid*65+m] = expf(A1[tid*65+m]-mx)*inv;
  }
  __syncthreads();
  for (int e=tid; e<4096; e+=256){
    int nn=e>>6, mm=e&63;
    float a = 0.5f*(A0[nn*65+mm]+A0[mm*65+nn]);
    A1[nn*65+mm] = a;
    Abf[e] = (short)f2bu(a);
  }
  __syncthreads();
  if (tid < 64){
    float s=0.f;
    for (int m=0;m<64;m++) s += A1[tid*65+m];
    rs_out[tid]=s;
  }
}

// ---------------------------------------------------------------------------
// K3: per-(b,n) transformer head via MFMA -> x_tat (bf16).
//     8 waves; wave w owns 16-row tiles {w, w+8}. LDS buffers reused:
//       tp_s: tin -> P -> f1 ;  q_s: Q -> ao ;  k_s: K -> h1 ;  v_t: V^T
// ---------------------------------------------------------------------------
__launch_bounds__(512, 1)
__global__ void k3_former(const float* __restrict__ x, const float* __restrict__ pe_g,
    const float* __restrict__ proj_w, const float* __restrict__ proj_b,
    const short* __restrict__ Wqkv_t, const float* __restrict__ bqkv,
    const short* __restrict__ Wo_t, const float* __restrict__ bo,
    const float* __restrict__ ln1g, const float* __restrict__ ln1b,
    const short* __restrict__ W1_t, const float* __restrict__ b1,
    const short* __restrict__ W2_t, const float* __restrict__ b2,
    const float* __restrict__ ln2g, const float* __restrict__ ln2b,
    const int* __restrict__ lengths, unsigned short* __restrict__ xtat)
{
  const int bn = blockIdx.x, b = bn>>6, n = bn&63;
  const int tid = threadIdx.x, w = tid>>6, lane = tid&63;
  const int l15 = lane&15, lhi = lane>>4;
  __shared__ short tp_s[16384];
  __shared__ short q_s[16384];
  __shared__ short k_s[16384];
  __shared__ short v_t[16384];
  __shared__ float valr[256], obsr[256];

  int len = lengths[b]; if (len<1) len=1;
  const int LT = (len+15)>>4;       // active 16-row tiles
  const int KB = (len+63)>>6;       // 64-key blocks

  if (tid < 256){
    const float* xr = x + ((size_t)b*256+tid)*129;
    valr[tid]=xr[n]; obsr[tid]=xr[64+n];
  }
  for (int e=tid; e<16384; e+=512) v_t[e]=0;   // guard against 0*NaN in PV tail
  __syncthreads();

  const int nrows = LT<<4;
  for (int e=tid; e<(nrows<<6); e+=512){
    int t=e>>6, d=e&63;
    float ti = fmaf(valr[t],proj_w[d], fmaf(obsr[t],proj_w[64+d], proj_b[d]))
             + pe_g[(((size_t)b<<8)+t)*64+d];
    tp_s[swzo(t,d)] = (short)f2bu(ti);
  }
  __syncthreads();

  // ---- QKV ----
  #pragma unroll
  for (int j=0;j<2;j++){
    const int rt = w + (j<<3);
    if (rt < LT){
      s16x8 a0 = ldfrag(tp_s, rt<<4, lane, 0);
      s16x8 a1 = ldfrag(tp_s, rt<<4, lane, 1);
      const int rb = (rt<<4) + (lhi<<2);
      #pragma unroll
      for (int nt=0; nt<12; nt++){
        const short* wb = Wqkv_t + (((nt<<4)+l15)<<6) + (lhi<<3);
        s16x8 b0 = *(const s16x8*)wb;
        s16x8 b1v = *(const s16x8*)(wb+32);
        float bias = bqkv[(nt<<4)+l15];
        f32x4 acc = {bias,bias,bias,bias};
        acc = __builtin_amdgcn_mfma_f32_16x16x32_bf16(a0,b0,acc,0,0,0);
        acc = __builtin_amdgcn_mfma_f32_16x16x32_bf16(a1,b1v,acc,0,0,0);
        const int col = ((nt&3)<<4) + l15;
        if (nt<4){
          #pragma unroll
          for(int i=0;i<4;i++) q_s[swzo(rb+i,col)] = (short)f2bu(acc[i]*0.125f);
        } else if (nt<8){
          #pragma unroll
          for(int i=0;i<4;i++) k_s[swzo(rb+i,col)] = (short)f2bu(acc[i]);
        } else {
          #pragma unroll
          for(int i=0;i<4;i++) v_t[swzv(col, rb+i)] = (short)f2bu(acc[i]);
        }
      }
    }
  }
  __syncthreads();

  // ---- attention: S=Q@K^T (chunks of 64 keys), P=exp masked, O += P@V ----
  f32x4 Oac[2][4];
  float rsum[2][4];
  #pragma unroll
  for(int j=0;j<2;j++)
    #pragma unroll
    for(int dt=0;dt<4;dt++) Oac[j][dt]=(f32x4){0.f,0.f,0.f,0.f};
  #pragma unroll
  for(int j=0;j<2;j++)
    #pragma unroll
    for(int i=0;i<4;i++) rsum[j][i]=0.f;

  for (int kb=0; kb<KB; kb++){
    s16x8 kf[4][2];
    #pragma unroll
    for (int ct=0;ct<4;ct++){
      kf[ct][0]=ldfrag(k_s, (((kb<<2)+ct)<<4), lane, 0);
      kf[ct][1]=ldfrag(k_s, (((kb<<2)+ct)<<4), lane, 1);
    }
    #pragma unroll
    for (int j=0;j<2;j++){
      const int rt=w+(j<<3);
      if (rt < LT){
        s16x8 q0=ldfrag(q_s, rt<<4, lane, 0);
        s16x8 q1=ldfrag(q_s, rt<<4, lane, 1);
        const int rb=(rt<<4)+(lhi<<2);
        #pragma unroll
        for (int ct=0;ct<4;ct++){
          f32x4 s={0.f,0.f,0.f,0.f};
          s=__builtin_amdgcn_mfma_f32_16x16x32_bf16(q0,kf[ct][0],s,0,0,0);
          s=__builtin_amdgcn_mfma_f32_16x16x32_bf16(q1,kf[ct][1],s,0,0,0);
          const int key=(kb<<6)+(ct<<4)+l15;
          #pragma unroll
          for(int i=0;i<4;i++){
            float p = (key<len) ? __expf(s[i]) : 0.f;
            rsum[j][i]+=p;
            tp_s[swzo(rb+i,(ct<<4)+l15)] = (short)f2bu(p);
          }
        }
      }
    }
    __syncthreads();
    s16x8 vf[4][2];
    #pragma unroll
    for (int dt=0;dt<4;dt++){
      const int d=(dt<<4)+l15;
      #pragma unroll
      for (int kk=0;kk<2;kk++){
        const int k0=(kk<<5)+(lhi<<3);
        vf[dt][kk] = *(const s16x8*)(v_t + swzv(d, (kb<<6)+k0));
      }
    }
    #pragma unroll
    for (int j=0;j<2;j++){
      const int rt=w+(j<<3);
      if (rt < LT){
        s16x8 p0=ldfrag(tp_s, rt<<4, lane, 0);
        s16x8 p1=ldfrag(tp_s, rt<<4, lane, 1);
        #pragma unroll
        for (int dt=0;dt<4;dt++){
          Oac[j][dt]=__builtin_amdgcn_mfma_f32_16x16x32_bf16(p0,vf[dt][0],Oac[j][dt],0,0,0);
          Oac[j][dt]=__builtin_amdgcn_mfma_f32_16x16x32_bf16(p1,vf[dt][1],Oac[j][dt],0,0,0);
        }
      }
    }
    __syncthreads();
  }

  // row-sum reduce (16 lanes holding the row's cols) -> 1/l
  float inv[2][4];
  #pragma unroll
  for(int j=0;j<2;j++)
    #pragma unroll
    for(int i=0;i<4;i++){
      float v=rsum[j][i];
      v += __shfl_xor(v,1); v += __shfl_xor(v,2); v += __shfl_xor(v,4); v += __shfl_xor(v,8);
      inv[j][i]=1.f/v;
    }

  // ao -> q_s (Q dead)
  #pragma unroll
  for (int j=0;j<2;j++){
    const int rt=w+(j<<3);
    if (rt < LT){
      const int rb=(rt<<4)+(lhi<<2);
      #pragma unroll
      for (int dt=0;dt<4;dt++)
        #pragma unroll
        for (int i=0;i<4;i++)
          q_s[swzo(rb+i,(dt<<4)+l15)] = (short)f2bu(Oac[j][dt][i]*inv[j][i]);
    }
  }
  __syncthreads();

  // h1 = LN1(tin + ao@Wo + bo); write bf16 h1 -> k_s (K dead), keep f32 regs
  f32x4 h1[2][4];
  #pragma unroll
  for (int j=0;j<2;j++){
    const int rt=w+(j<<3);
    if (rt < LT){
      s16x8 a0=ldfrag(q_s, rt<<4, lane, 0);
      s16x8 a1=ldfrag(q_s, rt<<4, lane, 1);
      const int rb=(rt<<4)+(lhi<<2);
      #pragma unroll
      for (int dt=0;dt<4;dt++){
        const int col=(dt<<4)+l15;
        const short* wb = Wo_t + (col<<6) + (lhi<<3);
        s16x8 b0=*(const s16x8*)wb, b1v=*(const s16x8*)(wb+32);
        float bias=bo[col];
        f32x4 acc={bias,bias,bias,bias};
        acc=__builtin_amdgcn_mfma_f32_16x16x32_bf16(a0,b0,acc,0,0,0);
        acc=__builtin_amdgcn_mfma_f32_16x16x32_bf16(a1,b1v,acc,0,0,0);
        #pragma unroll
        for(int i=0;i<4;i++){
          const int row=rb+i;
          acc[i]+= fmaf(valr[row],proj_w[col], fmaf(obsr[row],proj_w[64+col], proj_b[col]))
                 + pe_g[(((size_t)b<<8)+row)*64+col];
        }
        h1[j][dt]=acc;
      }
      f32x4 mu, rsq;
      #pragma unroll
      for(int i=0;i<4;i++){
        float sv = h1[j][0][i]+h1[j][1][i]+h1[j][2][i]+h1[j][3][i];
        sv += __shfl_xor(sv,1); sv+=__shfl_xor(sv,2); sv+=__shfl_xor(sv,4); sv+=__shfl_xor(sv,8);
        mu[i]=sv*(1.f/64.f);
      }
      #pragma unroll
      for(int i=0;i<4;i++){
        float sv=0.f;
        #pragma unroll
        for(int dt=0;dt<4;dt++){ float c=h1[j][dt][i]-mu[i]; sv=fmaf(c,c,sv); }
        sv += __shfl_xor(sv,1); sv+=__shfl_xor(sv,2); sv+=__shfl_xor(sv,4); sv+=__shfl_xor(sv,8);
        rsq[i]=1.f/sqrtf(sv*(1.f/64.f)+1e-5f);
      }
      #pragma unroll
      for(int dt=0;dt<4;dt++){
        const int col=(dt<<4)+l15;
        float g=ln1g[col], bb=ln1b[col];
        #pragma unroll
        for(int i=0;i<4;i++){
          float hv=(h1[j][dt][i]-mu[i])*rsq[i]*g+bb;
          h1[j][dt][i]=hv;
          k_s[swzo(rb+i,col)] = (short)f2bu(hv);
        }
      }
    }
  }
  __syncthreads();

  // FF1: f1 = relu(h1@W1+b1) -> tp_s
  #pragma unroll
  for (int j=0;j<2;j++){
    const int rt=w+(j<<3);
    if (rt < LT){
      s16x8 a0=ldfrag(k_s, rt<<4, lane, 0);
      s16x8 a1=ldfrag(k_s, rt<<4, lane, 1);
      const int rb=(rt<<4)+(lhi<<2);
      #pragma unroll
      for (int dt=0;dt<4;dt++){
        const int col=(dt<<4)+l15;
        const short* wb = W1_t + (col<<6)+(lhi<<3);
        s16x8 b0=*(const s16x8*)wb, b1v=*(const s16x8*)(wb+32);
        float bias=b1[col];
        f32x4 acc={bias,bias,bias,bias};
        acc=__builtin_amdgcn_mfma_f32_16x16x32_bf16(a0,b0,acc,0,0,0);
        acc=__builtin_amdgcn_mfma_f32_16x16x32_bf16(a1,b1v,acc,0,0,0);
        #pragma unroll
        for(int i=0;i<4;i++) tp_s[swzo(rb+i,col)]=(short)f2bu(fmaxf(acc[i],0.f));
      }
    }
  }
  __syncthreads();

  // FF2 + LN2 + mix + store
  #pragma unroll
  for (int j=0;j<2;j++){
    const int rt=w+(j<<3);
    if (rt < LT){
      s16x8 a0=ldfrag(tp_s, rt<<4, lane, 0);
      s16x8 a1=ldfrag(tp_s, rt<<4, lane, 1);
      const int rb=(rt<<4)+(lhi<<2);
      f32x4 to[4];
      #pragma unroll
      for (int dt=0;dt<4;dt++){
        const int col=(dt<<4)+l15;
        const short* wb = W2_t + (col<<6)+(lhi<<3);
        s16x8 b0=*(const s16x8*)wb, b1v=*(const s16x8*)(wb+32);
        float bias=b2[col];
        f32x4 acc={bias,bias,bias,bias};
        acc=__builtin_amdgcn_mfma_f32_16x16x32_bf16(a0,b0,acc,0,0,0);
        acc=__builtin_amdgcn_mfma_f32_16x16x32_bf16(a1,b1v,acc,0,0,0);
        acc += h1[j][dt];
        to[dt]=acc;
      }
      f32x4 mu, rsq;
      #pragma unroll
      for(int i=0;i<4;i++){
        float sv = to[0][i]+to[1][i]+to[2][i]+to[3][i];
        sv += __shfl_xor(sv,1); sv+=__shfl_xor(sv,2); sv+=__shfl_xor(sv,4); sv+=__shfl_xor(sv,8);
        mu[i]=sv*(1.f/64.f);
      }
      #pragma unroll
      for(int i=0;i<4;i++){
        float sv=0.f;
        #pragma unroll
        for(int dt=0;dt<4;dt++){ float c=to[dt][i]-mu[i]; sv=fmaf(c,c,sv); }
        sv += __shfl_xor(sv,1); sv+=__shfl_xor(sv,2); sv+=__shfl_xor(sv,4); sv+=__shfl_xor(sv,8);
        rsq[i]=1.f/sqrtf(sv*(1.f/64.f)+1e-5f);
      }
      #pragma unroll
      for(int dt=0;dt<4;dt++){
        const int col=(dt<<4)+l15;
        float g=ln2g[col], bb=ln2b[col];
        #pragma unroll
        for(int i=0;i<4;i++){
          const int row=rb+i;
          if (row < len){
            float tv=(to[dt][i]-mu[i])*rsq[i]*g+bb;
            float tin = fmaf(valr[row],proj_w[col], fmaf(obsr[row],proj_w[64+col], proj_b[col]))
                      + pe_g[(((size_t)b<<8)+row)*64+col];
            float ob = obsr[row];
            xtat[((size_t)bn<<14)+(row<<6)+col] = f2bu(ob*tin + (1.f-ob)*tv);
          }
        }
      }
    }
  }
}

// ---------------------------------------------------------------------------
// K4: graph-GRU scan, one block per batch, 8 waves, bf16 MFMA 16x16x32.
// ---------------------------------------------------------------------------
__launch_bounds__(512, 1)
__global__ void k4_scan(const unsigned short* __restrict__ xtat, const float* __restrict__ U,
                        const float* __restrict__ decay, const short* __restrict__ Abf,
                        const float* __restrict__ rs_g,
                        const float* __restrict__ Wz, const float* __restrict__ Wr,
                        const float* __restrict__ Wc,
                        const int* __restrict__ lengths, float* __restrict__ hT)
{
  const int b = blockIdx.x;
  const int tid = threadIdx.x;
  const int w = tid >> 6, lane = tid & 63;
  const int tn = w & 3, tm0 = (w >> 2) << 1;
  const int colg = (tn<<4) + (lane & 15);
  const int rsub = (lane >> 4) << 2;

  __shared__ short h_rm[4096], h_tp[4096], xt_rm[4096], xt_tp[4096];
  __shared__ short rh_rm[4096], rh_tp[4096], axt_s[4096], ah_s[4096], arh_s[4096];
  __shared__ float dec_s[256];
  __shared__ float rs_s[64];

  int len = lengths[b]; if (len < 1) len = 1;
  for (int e=tid; e<256; e+=512) dec_s[e] = decay[b*256+e];
  if (tid < 64) rs_s[tid] = rs_g[tid];

  s16x8 aA[2][2];
  #pragma unroll
  for (int ti=0;ti<2;ti++)
    #pragma unroll
    for (int kk=0;kk<2;kk++)
      aA[ti][kk] = *(const s16x8*)(Abf + (((tm0+ti)<<4) + (lane&15))*64 + (kk<<5) + ((lane>>4)<<3));

  s16x8 wf[12][2];
  {
    const float* Wg[3] = {Wz, Wr, Wc};
    const int offs[4] = {0, 64, 192, 256};
    #pragma unroll
    for (int g3=0; g3<3; g3++)
      #pragma unroll
      for (int s4=0; s4<4; s4++)
        #pragma unroll
        for (int kk=0; kk<2; kk++){
          s16x8 tf;
          int kb = (kk<<5) + ((lane>>4)<<3);
          #pragma unroll
          for (int j=0;j<8;j++)
            tf[j] = (short)f2bu(Wg[g3][(offs[s4]+kb+j)*64 + colg]);
          wf[g3*4+s4][kk] = tf;
        }
  }

  f32x4 hreg[2] = {{0.f,0.f,0.f,0.f},{0.f,0.f,0.f,0.f}};
  const int xn  = tid >> 3;
  const int xd0 = (tid & 7) << 3;
  __syncthreads();

  for (int t=0; t<256; t++){
    float dc = dec_s[t];
    #pragma unroll
    for (int ti=0;ti<2;ti++)
      #pragma unroll
      for (int i=0;i<4;i++) hreg[ti][i] *= dc;

    if (t < len){
      #pragma unroll
      for (int ti=0;ti<2;ti++){
        int rb = ((tm0+ti)<<4) + rsub;
        #pragma unroll
        for (int i=0;i<4;i++){
          short hv = (short)f2bu(hreg[ti][i]);
          h_rm[swzo(rb+i, colg)] = hv;
          h_tp[swzo(colg, rb+i)] = hv;
        }
      }
      {
        const s16x8 vv = *(const s16x8*)((const short*)xtat + (((size_t)(b*64+xn))*256 + t)*64 + xd0);
        *(s16x8*)(xt_rm + swzo(xn, xd0)) = vv;
        #pragma unroll
        for (int j=0;j<8;j++) xt_tp[swzo(xd0+j, xn)] = vv[j];
      }
      __syncthreads();

      {
        f32x4 ax[2] = {{0,0,0,0},{0,0,0,0}}, ahh[2] = {{0,0,0,0},{0,0,0,0}};
        #pragma unroll
        for (int kk=0;kk<2;kk++){
          s16x8 bx = ldfrag(xt_tp, tn<<4, lane, kk);
          s16x8 bh = ldfrag(h_tp,  tn<<4, lane, kk);
          #pragma unroll
          for (int ti=0;ti<2;ti++){
            ax[ti]  = __builtin_amdgcn_mfma_f32_16x16x32_bf16(aA[ti][kk], bx, ax[ti], 0,0,0);
            ahh[ti] = __builtin_amdgcn_mfma_f32_16x16x32_bf16(aA[ti][kk], bh, ahh[ti], 0,0,0);
          }
        }
        #pragma unroll
        for (int ti=0;ti<2;ti++){
          int rb = ((tm0+ti)<<4) + rsub;
          #pragma unroll
          for (int i=0;i<4;i++){
            axt_s[swzo(rb+i, colg)] = (short)f2bu(ax[ti][i]);
            ah_s [swzo(rb+i, colg)] = (short)f2bu(ahh[ti][i]);
          }
        }
      }
      __syncthreads();

      const float* ub = U + ((size_t)(b*256+t))*384;
      float u1z=ub[colg], u2z=ub[64+colg], u1r=ub[128+colg], u2r=ub[192+colg];
      float u1c=ub[256+colg], u2c=ub[320+colg];

      f32x4 gz[2] = {{0,0,0,0},{0,0,0,0}}, gr[2] = {{0,0,0,0},{0,0,0,0}};
      #pragma unroll
      for (int ti=0;ti<2;ti++){
        int rt = (tm0+ti)<<4;
        #pragma unroll
        for (int kk=0;kk<2;kk++){
          s16x8 fxt = ldfrag(xt_rm, rt, lane, kk);
          s16x8 fh  = ldfrag(h_rm,  rt, lane, kk);
          s16x8 fax = ldfrag(axt_s, rt, lane, kk);
          s16x8 fah = ldfrag(ah_s,  rt, lane, kk);
          gz[ti] = __builtin_amdgcn_mfma_f32_16x16x32_bf16(fxt, wf[0][kk], gz[ti], 0,0,0);
          gz[ti] = __builtin_amdgcn_mfma_f32_16x16x32_bf16(fh,  wf[1][kk], gz[ti], 0,0,0);
          gz[ti] = __builtin_amdgcn_mfma_f32_16x16x32_bf16(fax, wf[2][kk], gz[ti], 0,0,0);
          gz[ti] = __builtin_amdgcn_mfma_f32_16x16x32_bf16(fah, wf[3][kk], gz[ti], 0,0,0);
          gr[ti] = __builtin_amdgcn_mfma_f32_16x16x32_bf16(fxt, wf[4][kk], gr[ti], 0,0,0);
          gr[ti] = __builtin_amdgcn_mfma_f32_16x16x32_bf16(fh,  wf[5][kk], gr[ti], 0,0,0);
          gr[ti] = __builtin_amdgcn_mfma_f32_16x16x32_bf16(fax, wf[6][kk], gr[ti], 0,0,0);
          gr[ti] = __builtin_amdgcn_mfma_f32_16x16x32_bf16(fah, wf[7][kk], gr[ti], 0,0,0);
        }
      }
      f32x4 zz[2];
      #pragma unroll
      for (int ti=0;ti<2;ti++){
        int rb = ((tm0+ti)<<4) + rsub;
        #pragma unroll
        for (int i=0;i<4;i++){
          float rsv = rs_s[rb+i];
          float gzv = gz[ti][i] + u1z + rsv*u2z;
          float grv = gr[ti][i] + u1r + rsv*u2r;
          float zv = 1.f/(1.f+__expf(-gzv));
          float rv = 1.f/(1.f+__expf(-grv));
          zz[ti][i] = zv;
          short rhv = (short)f2bu(rv * hreg[ti][i]);
          rh_rm[swzo(rb+i, colg)] = rhv;
          rh_tp[swzo(colg, rb+i)] = rhv;
        }
      }
      __syncthreads();

      {
        f32x4 ar[2] = {{0,0,0,0},{0,0,0,0}};
        #pragma unroll
        for (int kk=0;kk<2;kk++){
          s16x8 brh = ldfrag(rh_tp, tn<<4, lane, kk);
          #pragma unroll
          for (int ti=0;ti<2;ti++)
            ar[ti] = __builtin_amdgcn_mfma_f32_16x16x32_bf16(aA[ti][kk], brh, ar[ti], 0,0,0);
        }
        #pragma unroll
        for (int ti=0;ti<2;ti++){
          int rb = ((tm0+ti)<<4) + rsub;
          #pragma unroll
          for (int i=0;i<4;i++)
            arh_s[swzo(rb+i, colg)] = (short)f2bu(ar[ti][i]);
        }
      }
      __syncthreads();

      {
        f32x4 gc[2] = {{0,0,0,0},{0,0,0,0}};
        #pragma unroll
        for (int ti=0;ti<2;ti++){
          int rt = (tm0+ti)<<4;
          #pragma unroll
          for (int kk=0;kk<2;kk++){
            s16x8 fxt = ldfrag(xt_rm, rt, lane, kk);
            s16x8 frh = ldfrag(rh_rm, rt, lane, kk);
            s16x8 fax = ldfrag(axt_s, rt, lane, kk);
            s16x8 far = ldfrag(arh_s, rt, lane, kk);
            gc[ti] = __builtin_amdgcn_mfma_f32_16x16x32_bf16(fxt, wf[8][kk],  gc[ti], 0,0,0);
            gc[ti] = __builtin_amdgcn_mfma_f32_16x16x32_bf16(frh, wf[9][kk],  gc[ti], 0,0,0);
            gc[ti] = __builtin_amdgcn_mfma_f32_16x16x32_bf16(fax, wf[10][kk], gc[ti], 0,0,0);
            gc[ti] = __builtin_amdgcn_mfma_f32_16x16x32_bf16(far, wf[11][kk], gc[ti], 0,0,0);
          }
        }
        #pragma unroll
        for (int ti=0;ti<2;ti++){
          int rb = ((tm0+ti)<<4) + rsub;
          #pragma unroll
          for (int i=0;i<4;i++){
            float rsv = rs_s[rb+i];
            float gcv = gc[ti][i] + u1c + rsv*u2c;
            float cv = 1.f - 2.f/(__expf(2.f*gcv)+1.f);
            float zv = zz[ti][i];
            hreg[ti][i] = zv*hreg[ti][i] + (1.f-zv)*cv;
          }
        }
      }
      __syncthreads();
    }
  }

  #pragma unroll
  for (int ti=0;ti<2;ti++){
    int rb = ((tm0+ti)<<4) + rsub;
    #pragma unroll
    for (int i=0;i<4;i++)
      hT[(((size_t)b<<6) + rb + i)*64 + colg] = hreg[ti][i];
  }
}

// ---------------------------------------------------------------------------
// K5: classifier head
// ---------------------------------------------------------------------------
__global__ void k5_head(const float* __restrict__ hT, const float* __restrict__ Wfin,
                        const float* __restrict__ bfin,
                        const float* __restrict__ stat, const float* __restrict__ We,
                        const float* __restrict__ be,
                        const float* __restrict__ Wc1, const float* __restrict__ bc1,
                        const float* __restrict__ Wc2, const float* __restrict__ bc2,
                        float* __restrict__ out)
{
  const int b = blockIdx.x, tid = threadIdx.x;
  __shared__ float cat[128];
  __shared__ float hcl[200];
  if (tid < 64){
    const float* hr = hT + (((size_t)b<<6)+tid)*64;
    float a = bfin[0];
    #pragma unroll
    for (int d=0;d<64;d++) a = fmaf(hr[d], Wfin[d], a);
    cat[tid]=a;
  } else if (tid < 128){
    int nn = tid-64;
    float a = be[nn];
    #pragma unroll
    for (int k=0;k<9;k++) a = fmaf(stat[b*9+k], We[k*64+nn], a);
    cat[tid]=a;
  }
  __syncthreads();
  if (tid < 200){
    float a = bc1[tid];
    for (int k=0;k<128;k++) a = fmaf(cat[k], Wc1[k*200+tid], a);
    hcl[tid] = fmaxf(a, 0.f);
  }
  __syncthreads();
  if (tid < 2){
    float a = bc2[tid];
    for (int k=0;k<200;k++) a = fmaf(hcl[k], Wc2[k*2+tid], a);
    out[b*2+tid] = a;
  }
}

// ---------------------------------------------------------------------------
extern "C" void kernel_launch(void* const* d_in, const int* in_sizes, int n_in,
                              void* d_out, int out_size, void* d_ws, size_t ws_size,
                              hipStream_t stream)
{
  const float* x       = (const float*)d_in[0];
  const float* nufft   = (const float*)d_in[1];
  const float* delta_t = (const float*)d_in[2];
  const float* stat    = (const float*)d_in[3];
  const int*   lengths = (const int*)  d_in[4];
  const float* proj_w  = (const float*)d_in[5];
  const float* proj_b  = (const float*)d_in[6];
  const float* Wqkv    = (const float*)d_in[7];
  const float* bqkv    = (const float*)d_in[8];
  const float* Wo      = (const float*)d_in[9];
  const float* bo      = (const float*)d_in[10];
  const float* ln1g    = (const float*)d_in[11];
  const float* ln1b    = (const float*)d_in[12];
  const float* W1      = (const float*)d_in[13];
  const float* b1      = (const float*)d_in[14];
  const float* W2      = (const float*)d_in[15];
  const float* b2      = (const float*)d_in[16];
  const float* ln2g    = (const float*)d_in[17];
  const float* ln2b    = (const float*)d_in[18];
  const float* WQf     = (const float*)d_in[19];
  const float* WKf     = (const float*)d_in[20];
  const float* Wz      = (const float*)d_in[21];
  const float* bz      = (const float*)d_in[22];
  const float* Wr      = (const float*)d_in[23];
  const float* br      = (const float*)d_in[24];
  const float* Wc      = (const float*)d_in[25];
  const float* bc      = (const float*)d_in[26];
  const float* Wfin    = (const float*)d_in[27];
  const float* bfin    = (const float*)d_in[28];
  const float* We      = (const float*)d_in[29];
  const float* be      = (const float*)d_in[30];
  const float* Wc1     = (const float*)d_in[31];
  const float* bc1     = (const float*)d_in[32];
  const float* Wc2     = (const float*)d_in[33];
  const float* bc2     = (const float*)d_in[34];
  float* out = (float*)d_out;

  char* ws = (char*)d_ws;
  size_t o = 0;
  float* pe    = (float*)(ws+o); o += (size_t)4096*64*4;
  float* U     = (float*)(ws+o); o += (size_t)4096*384*4;
  float* decay = (float*)(ws+o); o += (size_t)4096*4;
  unsigned short* xtat = (unsigned short*)(ws+o); o += (size_t)1024*256*64*2;
  float* qf    = (float*)(ws+o); o += (size_t)1024*256*4;
  float* kf    = (float*)(ws+o); o += (size_t)1024*256*4;
  float* soft  = (float*)(ws+o); o += (size_t)16*4096*4;
  short* Abf   = (short*)(ws+o); o += (size_t)4096*2;
  float* rs    = (float*)(ws+o); o += (size_t)64*4;
  float* hT    = (float*)(ws+o); o += (size_t)16*64*64*4;
  short* Wqkv_t= (short*)(ws+o); o += (size_t)12288*2;
  short* Wo_t  = (short*)(ws+o); o += (size_t)4096*2;
  short* W1_t  = (short*)(ws+o); o += (size_t)4096*2;
  short* W2_t  = (short*)(ws+o); o += (size_t)4096*2;
  (void)ws_size; (void)in_sizes; (void)n_in; (void)out_size;

  hipLaunchKernelGGL(k0_prep,   dim3(96),   dim3(256), 0, stream,
                     Wqkv, Wo, W1, W2, Wqkv_t, Wo_t, W1_t, W2_t);
  hipLaunchKernelGGL(k1_pe_u,   dim3(4096), dim3(64),  0, stream,
                     x, delta_t, Wz, bz, Wr, br, Wc, bc, pe, U, decay);
  hipLaunchKernelGGL(k2a_qfkf,  dim3(1024), dim3(256), 0, stream,
                     nufft, WQf, WKf, qf, kf);
  hipLaunchKernelGGL(k2b_soft,  dim3(16),   dim3(256), 0, stream, qf, kf, soft);
  hipLaunchKernelGGL(k2c_A,     dim3(1),    dim3(256), 0, stream, soft, Abf, rs);
  hipLaunchKernelGGL(k3_former, dim3(1024), dim3(512), 0, stream,
                     x, pe, proj_w, proj_b, Wqkv_t, bqkv, Wo_t, bo, ln1g, ln1b,
                     W1_t, b1, W2_t, b2, ln2g, ln2b, lengths, xtat);
  hipLaunchKernelGGL(k4_scan,   dim3(16),   dim3(512), 0, stream,
                     xtat, U, decay, Abf, rs, Wz, Wr, Wc, lengths, hT);
  hipLaunchKernelGGL(k5_head,   dim3(16),   dim3(256), 0, stream,
                     hT, Wfin, bfin, stat, We, be, Wc1, bc1, Wc2, bc2, out);
}